// Round 1
// baseline (378.121 us; speedup 1.0000x reference)
//
#include <hip/hip_runtime.h>
#include <hip/hip_bf16.h>

typedef __bf16 bf16x8 __attribute__((ext_vector_type(8)));
typedef __bf16 bf16x4 __attribute__((ext_vector_type(4)));
typedef float floatx4 __attribute__((ext_vector_type(4)));

__device__ __forceinline__ void load_lds16(const void* g, void* l) {
    __builtin_amdgcn_global_load_lds((const __attribute__((address_space(1))) void*)g,
                                     (__attribute__((address_space(3))) void*)l,
                                     16, 0, 0);
}

// ---------------- cast fp32 -> bf16 (vectorized) ----------------
__global__ __launch_bounds__(256) void cast_f32_bf16(const float* __restrict__ in,
                                                     __bf16* __restrict__ out, int n4) {
    int i = blockIdx.x * 256 + threadIdx.x;
    if (i < n4) {
        float4 v = ((const float4*)in)[i];
        bf16x4 o;
        o[0] = (__bf16)v.x; o[1] = (__bf16)v.y; o[2] = (__bf16)v.z; o[3] = (__bf16)v.w;
        ((bf16x4*)out)[i] = o;
    }
}

// ---------------- GEMM: C[M][N] = A[M][K] * B[N][K]^T (bf16 in, fp32 out) ----------------
// 128x128 tile, BK=32, 4 waves (2x2 of 64x64), 16x16x32 bf16 MFMA.
__global__ __launch_bounds__(256) void gemm_bt(const __bf16* __restrict__ A,
                                               const __bf16* __restrict__ B,
                                               float* __restrict__ C,
                                               int M, int N, int K) {
    __shared__ __attribute__((aligned(16))) __bf16 As[128 * 32];
    __shared__ __attribute__((aligned(16))) __bf16 Bs[128 * 32];

    int tid = threadIdx.x;
    int lane = tid & 63;
    int w = tid >> 6;
    int wm = (w >> 1) * 64;
    int wn = (w & 1) * 64;
    int bm0 = blockIdx.y * 128;
    int bn0 = blockIdx.x * 128;
    int r = lane & 15, q4 = lane >> 4;

    const __bf16* Ab = A + (size_t)(bm0 + (tid >> 2)) * K + (tid & 3) * 8;
    const __bf16* Bb = B + (size_t)(bn0 + (tid >> 2)) * K + (tid & 3) * 8;
    __bf16* AsT = &As[tid * 8];
    __bf16* BsT = &Bs[tid * 8];

    floatx4 acc[4][4];
#pragma unroll
    for (int i = 0; i < 4; i++)
#pragma unroll
        for (int j = 0; j < 4; j++) acc[i][j] = (floatx4)0.f;

    for (int k0 = 0; k0 < K; k0 += 32) {
        __syncthreads();
        load_lds16(Ab + k0, AsT);
        load_lds16(Ab + (size_t)64 * K + k0, AsT + 2048);
        load_lds16(Bb + k0, BsT);
        load_lds16(Bb + (size_t)64 * K + k0, BsT + 2048);
        __syncthreads();

        bf16x8 a[4], b[4];
#pragma unroll
        for (int mt = 0; mt < 4; mt++) a[mt] = *(const bf16x8*)&As[(wm + mt * 16 + r) * 32 + q4 * 8];
#pragma unroll
        for (int nt = 0; nt < 4; nt++) b[nt] = *(const bf16x8*)&Bs[(wn + nt * 16 + r) * 32 + q4 * 8];
#pragma unroll
        for (int mt = 0; mt < 4; mt++)
#pragma unroll
            for (int nt = 0; nt < 4; nt++)
                acc[mt][nt] = __builtin_amdgcn_mfma_f32_16x16x32_bf16(a[mt], b[nt], acc[mt][nt], 0, 0, 0);
    }

#pragma unroll
    for (int mt = 0; mt < 4; mt++)
#pragma unroll
        for (int nt = 0; nt < 4; nt++) {
            int row = bm0 + wm + mt * 16 + q4 * 4;
            int col = bn0 + wn + nt * 16 + r;
#pragma unroll
            for (int i = 0; i < 4; i++)
                C[(size_t)(row + i) * N + col] = acc[mt][nt][i];
        }
}

// ---------------- RoPE (neox) on q and k; q pre-scaled by head_dim^-0.5 ----------------
// qkv fp32 [2048][2560]; writes Qb [2048][2048] bf16 (roped*0.0625), Kb [2048][256] bf16 (roped).
__global__ __launch_bounds__(256) void rope_kernel(const float* __restrict__ qkv,
                                                   const int* __restrict__ positions,
                                                   __bf16* __restrict__ Qo,
                                                   __bf16* __restrict__ Ko) {
    int idx = blockIdx.x * 256 + threadIdx.x;
    if (idx >= 2048 * 9 * 128) return;
    int i = idx & 127;
    int th = idx >> 7;
    int head = th % 9;
    int t = th / 9;
    // inv_freq = 10000^(-i/128) = exp(-i * ln(10000)/128)
    float invf = expf(-(float)i * 0.07195578415606394f);
    float ang = (float)positions[t] * invf;
    float s = sinf(ang), c = cosf(ang);
    if (head < 8) {
        const float* src = qkv + (size_t)t * 2560 + head * 256;
        float x1 = src[i], x2 = src[i + 128];
        __bf16* dst = Qo + (size_t)t * 2048 + head * 256;
        dst[i]       = (__bf16)((x1 * c - x2 * s) * 0.0625f);
        dst[i + 128] = (__bf16)((x2 * c + x1 * s) * 0.0625f);
    } else {
        const float* src = qkv + (size_t)t * 2560 + 2048;
        float x1 = src[i], x2 = src[i + 128];
        __bf16* dst = Ko + (size_t)t * 256;
        dst[i]       = (__bf16)(x1 * c - x2 * s);
        dst[i + 128] = (__bf16)(x2 * c + x1 * s);
    }
}

// ---------------- V transpose: Vt[256][2048] bf16 from qkv v-slice ----------------
__global__ __launch_bounds__(256) void vtrans_kernel(const float* __restrict__ qkv,
                                                     __bf16* __restrict__ Vt) {
    __shared__ float tile[32][33];
    int bt = blockIdx.x;  // token tile 0..63
    int bc = blockIdx.y;  // channel tile 0..7
    int tx = threadIdx.x & 31;
    int ty0 = threadIdx.x >> 5;
#pragma unroll
    for (int ty = ty0; ty < 32; ty += 8)
        tile[ty][tx] = qkv[(size_t)(bt * 32 + ty) * 2560 + 2304 + bc * 32 + tx];
    __syncthreads();
#pragma unroll
    for (int ty = ty0; ty < 32; ty += 8)
        Vt[(size_t)(bc * 32 + ty) * 2048 + bt * 32 + tx] = (__bf16)tile[tx][ty];
}

// ---------------- Flash attention (causal, GQA 8:1, head_dim 256) ----------------
// grid: (32 q-tiles [reversed for balance], 8 heads). 4 waves; wave w owns Q rows [qt*64+w*16, +16).
// KV tile = 32. Q pre-scaled. Out bf16 [2048][2048].
__global__ __launch_bounds__(256) void attn_kernel(const __bf16* __restrict__ Q,
                                                   const __bf16* __restrict__ Kg,
                                                   const __bf16* __restrict__ Vt,
                                                   __bf16* __restrict__ O) {
    __shared__ __attribute__((aligned(16))) __bf16 Ks[32 * 256];   // [kv][d]
    __shared__ __attribute__((aligned(16))) __bf16 Vts[256 * 32];  // [d][kv]
    __shared__ __attribute__((aligned(16))) __bf16 Ps[4][16][32];  // per-wave P

    int qt = (int)(gridDim.x - 1 - blockIdx.x);  // longest first
    int h = blockIdx.y;
    int tid = threadIdx.x, lane = tid & 63, w = tid >> 6;
    int r = lane & 15, q4 = lane >> 4;

    bf16x8 qf[8];
    {
        const __bf16* qrow = Q + (size_t)(qt * 64 + w * 16 + r) * 2048 + h * 256 + q4 * 8;
#pragma unroll
        for (int ks = 0; ks < 8; ks++) qf[ks] = *(const bf16x8*)(qrow + ks * 32);
    }

    floatx4 acc[16];
#pragma unroll
    for (int i = 0; i < 16; i++) acc[i] = (floatx4)0.f;
    float m_i[4] = {-3e38f, -3e38f, -3e38f, -3e38f};
    float l_i[4] = {0.f, 0.f, 0.f, 0.f};

    int ntiles = qt * 2 + 2;
    for (int t = 0; t < ntiles; t++) {
        int kt0 = t * 32;
        __syncthreads();
#pragma unroll
        for (int j = 0; j < 4; j++)
            load_lds16(Kg + (size_t)(kt0 + j * 8 + (tid >> 5)) * 256 + (tid & 31) * 8,
                       &Ks[j * 2048 + tid * 8]);
#pragma unroll
        for (int j = 0; j < 4; j++)
            load_lds16(Vt + (size_t)(j * 64 + (tid >> 2)) * 2048 + kt0 + (tid & 3) * 8,
                       &Vts[j * 2048 + tid * 8]);
        __syncthreads();

        // S = Q K^T  (per wave: 16 rows x 32 kv)
        floatx4 s[2];
        s[0] = (floatx4)0.f; s[1] = (floatx4)0.f;
#pragma unroll
        for (int ks = 0; ks < 8; ks++) {
#pragma unroll
            for (int nt = 0; nt < 2; nt++) {
                bf16x8 kf = *(const bf16x8*)&Ks[(nt * 16 + r) * 256 + ks * 32 + q4 * 8];
                s[nt] = __builtin_amdgcn_mfma_f32_16x16x32_bf16(qf[ks], kf, s[nt], 0, 0, 0);
            }
        }
        // causal mask
        int qbase = qt * 64 + w * 16 + q4 * 4;
#pragma unroll
        for (int nt = 0; nt < 2; nt++) {
            int kpos = kt0 + nt * 16 + r;
#pragma unroll
            for (int i = 0; i < 4; i++)
                if (kpos > qbase + i) s[nt][i] = -3e38f;
        }
        // online softmax (row lives in one 16-lane group; reduce over width 16)
        float alpha[4];
#pragma unroll
        for (int i = 0; i < 4; i++) {
            float m = fmaxf(s[0][i], s[1][i]);
#pragma unroll
            for (int d = 1; d < 16; d <<= 1) m = fmaxf(m, __shfl_xor(m, d, 16));
            float mn = fmaxf(m_i[i], m);
            alpha[i] = __expf(m_i[i] - mn);
            m_i[i] = mn;
        }
        floatx4 p[2];
#pragma unroll
        for (int i = 0; i < 4; i++) {
            p[0][i] = __expf(s[0][i] - m_i[i]);
            p[1][i] = __expf(s[1][i] - m_i[i]);
            float sum = p[0][i] + p[1][i];
#pragma unroll
            for (int d = 1; d < 16; d <<= 1) sum += __shfl_xor(sum, d, 16);
            l_i[i] = l_i[i] * alpha[i] + sum;
        }
#pragma unroll
        for (int n16 = 0; n16 < 16; n16++)
#pragma unroll
            for (int i = 0; i < 4; i++) acc[n16][i] *= alpha[i];

        // P: C-layout -> LDS -> A-layout (intra-wave only; DS ops are in-order per wave)
#pragma unroll
        for (int nt = 0; nt < 2; nt++)
#pragma unroll
            for (int i = 0; i < 4; i++)
                Ps[w][q4 * 4 + i][nt * 16 + r] = (__bf16)p[nt][i];
        __builtin_amdgcn_wave_barrier();
        bf16x8 pf = *(const bf16x8*)&Ps[w][r][q4 * 8];
        __builtin_amdgcn_wave_barrier();

        // O += P V   (16 n-tiles of 16 over head_dim 256)
#pragma unroll
        for (int n16 = 0; n16 < 16; n16++) {
            bf16x8 vf = *(const bf16x8*)&Vts[(n16 * 16 + r) * 32 + q4 * 8];
            acc[n16] = __builtin_amdgcn_mfma_f32_16x16x32_bf16(pf, vf, acc[n16], 0, 0, 0);
        }
    }

#pragma unroll
    for (int n16 = 0; n16 < 16; n16++)
#pragma unroll
        for (int i = 0; i < 4; i++) {
            int row = qt * 64 + w * 16 + q4 * 4 + i;
            O[(size_t)row * 2048 + h * 256 + n16 * 16 + r] = (__bf16)(acc[n16][i] / l_i[i]);
        }
}

extern "C" void kernel_launch(void* const* d_in, const int* in_sizes, int n_in,
                              void* d_out, int out_size, void* d_ws, size_t ws_size,
                              hipStream_t stream) {
    const int* positions = (const int*)d_in[0];
    const float* hidden  = (const float*)d_in[1];
    const float* Wqkv    = (const float*)d_in[2];
    const float* Wo      = (const float*)d_in[3];
    float* out = (float*)d_out;

    char* ws = (char*)d_ws;
    size_t off = 0;
    __bf16* Ah    = (__bf16*)(ws + off); off += (size_t)2048 * 2048 * 2;  // 8 MB
    __bf16* Wqkvh = (__bf16*)(ws + off); off += (size_t)2560 * 2048 * 2;  // 10 MB
    __bf16* Woh   = (__bf16*)(ws + off); off += (size_t)2048 * 2048 * 2;  // 8 MB
    float*  qkv   = (float*) (ws + off); off += (size_t)2048 * 2560 * 4;  // 20 MB
    __bf16* Qb    = (__bf16*)(ws + off); off += (size_t)2048 * 2048 * 2;  // 8 MB
    __bf16* Kb    = (__bf16*)(ws + off); off += (size_t)2048 * 256 * 2;   // 1 MB
    __bf16* Vtb   = (__bf16*)(ws + off); off += (size_t)256 * 2048 * 2;   // 1 MB
    __bf16* attnb = Ah;  // Ah dead after GEMM1; reuse for attention output

    cast_f32_bf16<<<4096, 256, 0, stream>>>(hidden, Ah, 1048576);
    cast_f32_bf16<<<5120, 256, 0, stream>>>(Wqkv, Wqkvh, 1310720);
    cast_f32_bf16<<<4096, 256, 0, stream>>>(Wo, Woh, 1048576);

    // qkv = hidden @ Wqkv^T
    gemm_bt<<<dim3(20, 16), 256, 0, stream>>>(Ah, Wqkvh, qkv, 2048, 2560, 2048);

    rope_kernel<<<9216, 256, 0, stream>>>(qkv, positions, Qb, Kb);
    vtrans_kernel<<<dim3(64, 8), 256, 0, stream>>>(qkv, Vtb);

    attn_kernel<<<dim3(32, 8), 256, 0, stream>>>(Qb, Kb, Vtb, attnb);

    // out = attn @ Wo^T
    gemm_bt<<<dim3(16, 16), 256, 0, stream>>>(attnb, Woh, out, 2048, 2048, 2048);
}

// Round 2
// 291.429 us; speedup vs baseline: 1.2975x; 1.2975x over previous
//
#include <hip/hip_runtime.h>
#include <hip/hip_bf16.h>

typedef __bf16 bf16x8 __attribute__((ext_vector_type(8)));
typedef __bf16 bf16x4 __attribute__((ext_vector_type(4)));
typedef float floatx4 __attribute__((ext_vector_type(4)));

__device__ __forceinline__ void load_lds16(const void* g, void* l) {
    __builtin_amdgcn_global_load_lds((const __attribute__((address_space(1))) void*)g,
                                     (__attribute__((address_space(3))) void*)l,
                                     16, 0, 0);
}

// ---------------- fused cast fp32 -> bf16 for all three weight/input tensors ----------------
__global__ __launch_bounds__(256) void cast_all(const float* __restrict__ hid,
                                                const float* __restrict__ wqkv,
                                                const float* __restrict__ wo,
                                                __bf16* __restrict__ Ah,
                                                __bf16* __restrict__ Wqkvh,
                                                __bf16* __restrict__ Woh) {
    const int n1 = 1048576, n2 = 1310720;  // float4 counts: hidden, Wqkv (Wo = n1)
    int i = blockIdx.x * 256 + threadIdx.x;
    const float* in;
    __bf16* out;
    int j;
    if (i < n1) { in = hid; out = Ah; j = i; }
    else if (i < n1 + n2) { in = wqkv; out = Wqkvh; j = i - n1; }
    else { in = wo; out = Woh; j = i - n1 - n2; }
    float4 v = ((const float4*)in)[j];
    bf16x4 o;
    o[0] = (__bf16)v.x; o[1] = (__bf16)v.y; o[2] = (__bf16)v.z; o[3] = (__bf16)v.w;
    ((bf16x4*)out)[j] = o;
}

// ---------------- GEMM: C[M][N] = A[M][K] * B[N][K]^T (bf16 in, fp32 out) ----------------
// 128x128 tile, BK=64, 4 waves (2x2 of 64x64). Fragment-order LDS: chunk c (1KB) holds
// elements so that ds_read_b128 fragment fetches are lane-contiguous (no bank conflicts).
__global__ __launch_bounds__(256) void gemm_bt(const __bf16* __restrict__ A,
                                               const __bf16* __restrict__ B,
                                               float* __restrict__ C,
                                               int M, int N, int K) {
    __shared__ __attribute__((aligned(16))) __bf16 As[128 * 64];
    __shared__ __attribute__((aligned(16))) __bf16 Bs[128 * 64];

    int tid = threadIdx.x;
    int lane = tid & 63;
    int w = tid >> 6;
    int wm = (w >> 1) * 64;
    int wn = (w & 1) * 64;
    int bm0 = blockIdx.y * 128;
    int bn0 = blockIdx.x * 128;
    int r = lane & 15, q4 = lane >> 4;
    int rr = lane >> 2, qq = lane & 3;

    floatx4 acc[4][4];
#pragma unroll
    for (int i = 0; i < 4; i++)
#pragma unroll
        for (int j = 0; j < 4; j++) acc[i][j] = (floatx4)0.f;

    for (int k0 = 0; k0 < K; k0 += 64) {
        __syncthreads();
#pragma unroll
        for (int j = 0; j < 4; j++) {
            int c = w * 4 + j;          // chunk 0..15
            int kk = c >> 3, g = c & 7; // kk: 32-wide k half; g: 16-row group
            load_lds16(A + (size_t)(bm0 + g * 16 + rr) * K + k0 + kk * 32 + qq * 8,
                       &As[c * 512 + lane * 8]);
            load_lds16(B + (size_t)(bn0 + g * 16 + rr) * K + k0 + kk * 32 + qq * 8,
                       &Bs[c * 512 + lane * 8]);
        }
        __syncthreads();

#pragma unroll
        for (int kk = 0; kk < 2; kk++) {
            bf16x8 a[4], b[4];
#pragma unroll
            for (int mt = 0; mt < 4; mt++)
                a[mt] = *(const bf16x8*)&As[(kk * 8 + (wm >> 4) + mt) * 512 + r * 32 + q4 * 8];
#pragma unroll
            for (int nt = 0; nt < 4; nt++)
                b[nt] = *(const bf16x8*)&Bs[(kk * 8 + (wn >> 4) + nt) * 512 + r * 32 + q4 * 8];
#pragma unroll
            for (int mt = 0; mt < 4; mt++)
#pragma unroll
                for (int nt = 0; nt < 4; nt++)
                    acc[mt][nt] = __builtin_amdgcn_mfma_f32_16x16x32_bf16(a[mt], b[nt], acc[mt][nt], 0, 0, 0);
        }
    }

#pragma unroll
    for (int mt = 0; mt < 4; mt++)
#pragma unroll
        for (int nt = 0; nt < 4; nt++) {
            int row = bm0 + wm + mt * 16 + q4 * 4;
            int col = bn0 + wn + nt * 16 + r;
#pragma unroll
            for (int i = 0; i < 4; i++)
                C[(size_t)(row + i) * N + col] = acc[mt][nt][i];
        }
}

// ---------------- RoPE (neox) on q and k; q pre-scaled by head_dim^-0.5 ----------------
__global__ __launch_bounds__(256) void rope_kernel(const float* __restrict__ qkv,
                                                   const int* __restrict__ positions,
                                                   __bf16* __restrict__ Qo,
                                                   __bf16* __restrict__ Ko) {
    int idx = blockIdx.x * 256 + threadIdx.x;
    if (idx >= 2048 * 9 * 128) return;
    int i = idx & 127;
    int th = idx >> 7;
    int head = th % 9;
    int t = th / 9;
    float invf = expf(-(float)i * 0.07195578415606394f);  // 10000^(-i/128)
    float ang = (float)positions[t] * invf;
    float s = sinf(ang), c = cosf(ang);
    if (head < 8) {
        const float* src = qkv + (size_t)t * 2560 + head * 256;
        float x1 = src[i], x2 = src[i + 128];
        __bf16* dst = Qo + (size_t)t * 2048 + head * 256;
        dst[i]       = (__bf16)((x1 * c - x2 * s) * 0.0625f);
        dst[i + 128] = (__bf16)((x2 * c + x1 * s) * 0.0625f);
    } else {
        const float* src = qkv + (size_t)t * 2560 + 2048;
        float x1 = src[i], x2 = src[i + 128];
        __bf16* dst = Ko + (size_t)t * 256;
        dst[i]       = (__bf16)(x1 * c - x2 * s);
        dst[i + 128] = (__bf16)(x2 * c + x1 * s);
    }
}

// ---------------- V transpose: Vt[256][2048] bf16 from qkv v-slice ----------------
__global__ __launch_bounds__(256) void vtrans_kernel(const float* __restrict__ qkv,
                                                     __bf16* __restrict__ Vt) {
    __shared__ float tile[32][33];
    int bt = blockIdx.x;  // token tile 0..63
    int bc = blockIdx.y;  // channel tile 0..7
    int tx = threadIdx.x & 31;
    int ty0 = threadIdx.x >> 5;
#pragma unroll
    for (int ty = ty0; ty < 32; ty += 8)
        tile[ty][tx] = qkv[(size_t)(bt * 32 + ty) * 2560 + 2304 + bc * 32 + tx];
    __syncthreads();
#pragma unroll
    for (int ty = ty0; ty < 32; ty += 8)
        Vt[(size_t)(bc * 32 + ty) * 2048 + bt * 32 + tx] = (__bf16)tile[tx][ty];
}

// ---------------- Flash attention, KV-split (flash-decoding) ----------------
// grid (32 qtiles [reversed], 8 heads, 4 kv-splits). Block: 4 waves, wave w owns Q rows
// [qt*64+w*16, +16). KV chunk = 512 tokens = up to 16 tiles of 32. Writes UNNORMALIZED
// partial O (bf16) + (m,l) f32 per row; combine_kernel merges.
// Partial slot compaction: valid (qt,s) iff 8*s <= qt.
__constant__ int c_sbase[4] = {0, 32, 56, 72};
__constant__ int c_minqt[4] = {0, 8, 16, 24};

__global__ __launch_bounds__(256) void attn_kernel(const __bf16* __restrict__ Q,
                                                   const __bf16* __restrict__ Kg,
                                                   const __bf16* __restrict__ Vt,
                                                   __bf16* __restrict__ Opart,
                                                   float2* __restrict__ Ml) {
    __shared__ __attribute__((aligned(16))) __bf16 Ks[32 * 256];   // fragment-order chunks
    __shared__ __attribute__((aligned(16))) __bf16 Vs[32 * 256];   // fragment-order chunks
    __shared__ __attribute__((aligned(16))) __bf16 Ps[4][16][32];  // per-wave P

    int qt = 31 - (int)blockIdx.x;  // longest first
    int h = blockIdx.y;
    int s = blockIdx.z;
    int start = s * 512;
    int end = (qt + 1) * 64;
    if (end > start + 512) end = start + 512;
    if (start >= end) return;

    int tid = threadIdx.x, lane = tid & 63, w = tid >> 6;
    int r = lane & 15, q4 = lane >> 4;
    int rr = lane >> 2, qq = lane & 3;

    bf16x8 qf[8];
    {
        const __bf16* qrow = Q + (size_t)(qt * 64 + w * 16 + r) * 2048 + h * 256 + q4 * 8;
#pragma unroll
        for (int ks = 0; ks < 8; ks++) qf[ks] = *(const bf16x8*)(qrow + ks * 32);
    }

    floatx4 acc[16];
#pragma unroll
    for (int i = 0; i < 16; i++) acc[i] = (floatx4)0.f;
    float m_i[4] = {-3e38f, -3e38f, -3e38f, -3e38f};
    float l_i[4] = {0.f, 0.f, 0.f, 0.f};

    for (int kt0 = start; kt0 < end; kt0 += 32) {
        __syncthreads();
        // K tile 32x256 -> 16 chunks of 1KB, fragment order; wave w stages chunks w*4..w*4+3
#pragma unroll
        for (int j = 0; j < 4; j++) {
            int c = w * 4 + j;
            int ks = c >> 1, nt = c & 1;
            load_lds16(Kg + (size_t)(kt0 + nt * 16 + rr) * 256 + ks * 32 + qq * 8,
                       &Ks[c * 512 + lane * 8]);
            // V tile (as Vt rows = head-dim): chunk c = n16 group
            load_lds16(Vt + (size_t)(c * 16 + rr) * 2048 + kt0 + qq * 8,
                       &Vs[c * 512 + lane * 8]);
        }
        __syncthreads();

        // S = Q K^T  (per wave: 16 rows x 32 kv)
        floatx4 sc[2];
        sc[0] = (floatx4)0.f; sc[1] = (floatx4)0.f;
#pragma unroll
        for (int ks = 0; ks < 8; ks++) {
#pragma unroll
            for (int nt = 0; nt < 2; nt++) {
                bf16x8 kf = *(const bf16x8*)&Ks[(ks * 2 + nt) * 512 + r * 32 + q4 * 8];
                sc[nt] = __builtin_amdgcn_mfma_f32_16x16x32_bf16(qf[ks], kf, sc[nt], 0, 0, 0);
            }
        }
        // causal mask
        int qbase = qt * 64 + w * 16 + q4 * 4;
#pragma unroll
        for (int nt = 0; nt < 2; nt++) {
            int kpos = kt0 + nt * 16 + r;
#pragma unroll
            for (int i = 0; i < 4; i++)
                if (kpos > qbase + i) sc[nt][i] = -3e38f;
        }
        // online softmax (row lives in one 16-lane group)
        float alpha[4];
#pragma unroll
        for (int i = 0; i < 4; i++) {
            float m = fmaxf(sc[0][i], sc[1][i]);
#pragma unroll
            for (int d = 1; d < 16; d <<= 1) m = fmaxf(m, __shfl_xor(m, d, 16));
            float mn = fmaxf(m_i[i], m);
            alpha[i] = __expf(m_i[i] - mn);
            m_i[i] = mn;
        }
        floatx4 p[2];
#pragma unroll
        for (int i = 0; i < 4; i++) {
            p[0][i] = __expf(sc[0][i] - m_i[i]);
            p[1][i] = __expf(sc[1][i] - m_i[i]);
            float sum = p[0][i] + p[1][i];
#pragma unroll
            for (int d = 1; d < 16; d <<= 1) sum += __shfl_xor(sum, d, 16);
            l_i[i] = l_i[i] * alpha[i] + sum;
        }
#pragma unroll
        for (int n16 = 0; n16 < 16; n16++)
#pragma unroll
            for (int i = 0; i < 4; i++) acc[n16][i] *= alpha[i];

        // P: C-layout -> LDS -> A-layout (intra-wave; DS same-wave ops are in order)
#pragma unroll
        for (int nt = 0; nt < 2; nt++)
#pragma unroll
            for (int i = 0; i < 4; i++)
                Ps[w][q4 * 4 + i][nt * 16 + r] = (__bf16)p[nt][i];
        __builtin_amdgcn_wave_barrier();
        bf16x8 pf = *(const bf16x8*)&Ps[w][r][q4 * 8];
        __builtin_amdgcn_wave_barrier();

        // O += P V
#pragma unroll
        for (int n16 = 0; n16 < 16; n16++) {
            bf16x8 vf = *(const bf16x8*)&Vs[n16 * 512 + r * 32 + q4 * 8];
            acc[n16] = __builtin_amdgcn_mfma_f32_16x16x32_bf16(pf, vf, acc[n16], 0, 0, 0);
        }
    }

    // write unnormalized partials
    int pidx = c_sbase[s] + qt - c_minqt[s];
    size_t base = (((size_t)pidx * 8 + h) * 64);
#pragma unroll
    for (int n16 = 0; n16 < 16; n16++)
#pragma unroll
        for (int i = 0; i < 4; i++) {
            int rowin = w * 16 + q4 * 4 + i;
            Opart[(base + rowin) * 256 + n16 * 16 + r] = (__bf16)acc[n16][i];
        }
    if (r == 0) {
#pragma unroll
        for (int i = 0; i < 4; i++) {
            int rowin = w * 16 + q4 * 4 + i;
            Ml[base + rowin] = make_float2(m_i[i], l_i[i]);
        }
    }
}

// ---------------- combine partials -> attn output (bf16 [2048][2048]) ----------------
__global__ __launch_bounds__(256) void combine_kernel(const __bf16* __restrict__ Opart,
                                                      const float2* __restrict__ Ml,
                                                      __bf16* __restrict__ attnb) {
    int wid = blockIdx.x * 4 + (threadIdx.x >> 6);  // 0..16383 = (t,h)
    int lane = threadIdx.x & 63;
    int t = wid >> 3, h = wid & 7;
    int qt = t >> 6, row = t & 63;
    int smax = qt >> 3; if (smax > 3) smax = 3;

    float ms[4], ls[4];
    size_t rbase[4];
    float M = -3e38f;
    for (int s = 0; s <= smax; s++) {
        int pidx = c_sbase[s] + qt - c_minqt[s];
        rbase[s] = ((size_t)pidx * 8 + h) * 64 + row;
        float2 ml = Ml[rbase[s]];
        ms[s] = ml.x; ls[s] = ml.y;
        M = fmaxf(M, ml.x);
    }
    float L = 0.f;
    float o[4] = {0.f, 0.f, 0.f, 0.f};
    for (int s = 0; s <= smax; s++) {
        float wsc = __expf(ms[s] - M);
        L += ls[s] * wsc;
        bf16x4 v = *(const bf16x4*)&Opart[rbase[s] * 256 + lane * 4];
#pragma unroll
        for (int j = 0; j < 4; j++) o[j] += wsc * (float)v[j];
    }
    float inv = 1.f / L;
    bf16x4 ov;
#pragma unroll
    for (int j = 0; j < 4; j++) ov[j] = (__bf16)(o[j] * inv);
    *(bf16x4*)&attnb[(size_t)t * 2048 + h * 256 + lane * 4] = ov;
}

extern "C" void kernel_launch(void* const* d_in, const int* in_sizes, int n_in,
                              void* d_out, int out_size, void* d_ws, size_t ws_size,
                              hipStream_t stream) {
    const int* positions = (const int*)d_in[0];
    const float* hidden  = (const float*)d_in[1];
    const float* Wqkv    = (const float*)d_in[2];
    const float* Wo      = (const float*)d_in[3];
    float* out = (float*)d_out;

    char* ws = (char*)d_ws;
    // Layout (<= 56 MB, proven available):
    // [0,8)    Ah (bf16 hidden; reused as attnb after GEMM1)
    // [8,16)   Woh
    // [16,26)  Wqkvh  --+ dead after GEMM1/rope: overlaid by Opart+Ml (21.3 MB)
    // [26,46)  qkv    --+
    // [46,54)  Qb
    // [54,55)  Kb
    // [55,56)  Vtb
    const size_t MB = 1024 * 1024;
    __bf16* Ah    = (__bf16*)(ws + 0 * MB);
    __bf16* Woh   = (__bf16*)(ws + 8 * MB);
    __bf16* Wqkvh = (__bf16*)(ws + 16 * MB);
    float*  qkv   = (float*) (ws + 26 * MB);
    __bf16* Qb    = (__bf16*)(ws + 46 * MB);
    __bf16* Kb    = (__bf16*)(ws + 54 * MB);
    __bf16* Vtb   = (__bf16*)(ws + 55 * MB);
    __bf16* Opart = (__bf16*)(ws + 16 * MB);                       // 20.97 MB
    float2* Ml    = (float2*)(ws + 16 * MB + 21 * MB);             // 0.33 MB
    __bf16* attnb = Ah;

    cast_all<<<13312, 256, 0, stream>>>(hidden, Wqkv, Wo, Ah, Wqkvh, Woh);

    // qkv = hidden @ Wqkv^T
    gemm_bt<<<dim3(20, 16), 256, 0, stream>>>(Ah, Wqkvh, qkv, 2048, 2560, 2048);

    rope_kernel<<<9216, 256, 0, stream>>>(qkv, positions, Qb, Kb);
    vtrans_kernel<<<dim3(64, 8), 256, 0, stream>>>(qkv, Vtb);

    attn_kernel<<<dim3(32, 8, 4), 256, 0, stream>>>(Qb, Kb, Vtb, Opart, Ml);
    combine_kernel<<<4096, 256, 0, stream>>>(Opart, Ml, attnb);

    // out = attn @ Wo^T
    gemm_bt<<<dim3(16, 16), 256, 0, stream>>>(attnb, Woh, out, 2048, 2048, 2048);
}

// Round 3
// 288.722 us; speedup vs baseline: 1.3096x; 1.0094x over previous
//
#include <hip/hip_runtime.h>
#include <hip/hip_bf16.h>

typedef __bf16 bf16x8 __attribute__((ext_vector_type(8)));
typedef __bf16 bf16x4 __attribute__((ext_vector_type(4)));
typedef float floatx4 __attribute__((ext_vector_type(4)));

// barrier that drains LDS only — vmem prefetches stay in flight (the AITER trick)
__device__ __forceinline__ void barrier_lgkm() {
    asm volatile("s_waitcnt lgkmcnt(0)\n\ts_barrier" ::: "memory");
}

// ---------------- fused cast fp32 -> bf16 ----------------
__global__ __launch_bounds__(256) void cast_all(const float* __restrict__ hid,
                                                const float* __restrict__ wqkv,
                                                const float* __restrict__ wo,
                                                __bf16* __restrict__ Ah,
                                                __bf16* __restrict__ Wqkvh,
                                                __bf16* __restrict__ Woh) {
    const int n1 = 1048576, n2 = 1310720;
    int i = blockIdx.x * 256 + threadIdx.x;
    const float* in;
    __bf16* out;
    int j;
    if (i < n1) { in = hid; out = Ah; j = i; }
    else if (i < n1 + n2) { in = wqkv; out = Wqkvh; j = i - n1; }
    else { in = wo; out = Woh; j = i - n1 - n2; }
    float4 v = ((const float4*)in)[j];
    bf16x4 o;
    o[0] = (__bf16)v.x; o[1] = (__bf16)v.y; o[2] = (__bf16)v.z; o[3] = (__bf16)v.w;
    ((bf16x4*)out)[j] = o;
}

// ---------------- split-K GEMM: Cpart[M][N] (bf16) = A[M][kslice] * B[N][kslice]^T ----------------
// 128x128 tile, BK=64, grid.z = k-slice. VGPR prefetch + ds_write, padded LDS (stride 72),
// lgkm-only barriers: global loads for iter t+1 overlap iter t compute.
__global__ __launch_bounds__(256) void gemm_bt_splitk(const __bf16* __restrict__ A,
                                                      const __bf16* __restrict__ B,
                                                      __bf16* __restrict__ C,
                                                      int M, int N, int K) {
    __shared__ __attribute__((aligned(16))) __bf16 As[128 * 72];
    __shared__ __attribute__((aligned(16))) __bf16 Bs[128 * 72];

    int tid = threadIdx.x, lane = tid & 63, w = tid >> 6;
    int wm = (w >> 1) * 64, wn = (w & 1) * 64;
    int bm0 = blockIdx.y * 128, bn0 = blockIdx.x * 128;
    int r = lane & 15, q4 = lane >> 4;
    int Khalf = K >> 1;
    int kbase = (int)blockIdx.z * Khalf;

    int srow = tid & 127;
    int scol = (tid >> 7) * 32;
    const __bf16* Ag = A + (size_t)(bm0 + srow) * K + kbase + scol;
    const __bf16* Bg = B + (size_t)(bn0 + srow) * K + kbase + scol;
    __bf16* Asd = &As[srow * 72 + scol];
    __bf16* Bsd = &Bs[srow * 72 + scol];

    floatx4 acc[4][4];
#pragma unroll
    for (int i = 0; i < 4; i++)
#pragma unroll
        for (int j = 0; j < 4; j++) acc[i][j] = (floatx4)0.f;

    bf16x8 ar[4], br[4];
#pragma unroll
    for (int j = 0; j < 4; j++) {
        ar[j] = *(const bf16x8*)(Ag + j * 8);
        br[j] = *(const bf16x8*)(Bg + j * 8);
    }

    for (int k0 = 0; k0 < Khalf; k0 += 64) {
        barrier_lgkm();
#pragma unroll
        for (int j = 0; j < 4; j++) {
            *(bf16x8*)(Asd + j * 8) = ar[j];
            *(bf16x8*)(Bsd + j * 8) = br[j];
        }
        if (k0 + 64 < Khalf) {
#pragma unroll
            for (int j = 0; j < 4; j++) {
                ar[j] = *(const bf16x8*)(Ag + k0 + 64 + j * 8);
                br[j] = *(const bf16x8*)(Bg + k0 + 64 + j * 8);
            }
        }
        barrier_lgkm();
#pragma unroll
        for (int kk = 0; kk < 2; kk++) {
            bf16x8 a[4], b[4];
#pragma unroll
            for (int mt = 0; mt < 4; mt++)
                a[mt] = *(const bf16x8*)&As[(wm + mt * 16 + r) * 72 + kk * 32 + q4 * 8];
#pragma unroll
            for (int nt = 0; nt < 4; nt++)
                b[nt] = *(const bf16x8*)&Bs[(wn + nt * 16 + r) * 72 + kk * 32 + q4 * 8];
#pragma unroll
            for (int mt = 0; mt < 4; mt++)
#pragma unroll
                for (int nt = 0; nt < 4; nt++)
                    acc[mt][nt] = __builtin_amdgcn_mfma_f32_16x16x32_bf16(a[mt], b[nt], acc[mt][nt], 0, 0, 0);
        }
    }

    __bf16* Cp = C + (size_t)blockIdx.z * M * N;
#pragma unroll
    for (int mt = 0; mt < 4; mt++)
#pragma unroll
        for (int nt = 0; nt < 4; nt++) {
            int row = bm0 + wm + mt * 16 + q4 * 4;
            int col = bn0 + wn + nt * 16 + r;
#pragma unroll
            for (int i = 0; i < 4; i++)
                Cp[(size_t)(row + i) * N + col] = (__bf16)acc[mt][nt][i];
        }
}

// ---------------- RoPE on q,k (reads bf16 split-K partials, adds) ----------------
__global__ __launch_bounds__(256) void rope_kernel(const __bf16* __restrict__ qa,
                                                   const __bf16* __restrict__ qb,
                                                   const int* __restrict__ positions,
                                                   __bf16* __restrict__ Qo,
                                                   __bf16* __restrict__ Ko) {
    int idx = blockIdx.x * 256 + threadIdx.x;
    if (idx >= 2048 * 9 * 128) return;
    int i = idx & 127;
    int th = idx >> 7;
    int head = th % 9;
    int t = th / 9;
    float invf = expf(-(float)i * 0.07195578415606394f);  // 10000^(-i/128)
    float ang = (float)positions[t] * invf;
    float s = sinf(ang), c = cosf(ang);
    size_t off = (size_t)t * 2560 + (head < 8 ? head * 256 : 2048);
    float x1 = (float)qa[off + i] + (float)qb[off + i];
    float x2 = (float)qa[off + i + 128] + (float)qb[off + i + 128];
    if (head < 8) {
        __bf16* dst = Qo + (size_t)t * 2048 + head * 256;
        dst[i]       = (__bf16)((x1 * c - x2 * s) * 0.0625f);
        dst[i + 128] = (__bf16)((x2 * c + x1 * s) * 0.0625f);
    } else {
        __bf16* dst = Ko + (size_t)t * 256;
        dst[i]       = (__bf16)(x1 * c - x2 * s);
        dst[i + 128] = (__bf16)(x2 * c + x1 * s);
    }
}

// ---------------- V transpose (adds split-K partials): Vt[256][2048] ----------------
__global__ __launch_bounds__(256) void vtrans_kernel(const __bf16* __restrict__ qa,
                                                     const __bf16* __restrict__ qb,
                                                     __bf16* __restrict__ Vt) {
    __shared__ float tile[32][33];
    int bt = blockIdx.x;
    int bc = blockIdx.y;
    int tx = threadIdx.x & 31;
    int ty0 = threadIdx.x >> 5;
#pragma unroll
    for (int ty = ty0; ty < 32; ty += 8) {
        size_t gi = (size_t)(bt * 32 + ty) * 2560 + 2304 + bc * 32 + tx;
        tile[ty][tx] = (float)qa[gi] + (float)qb[gi];
    }
    __syncthreads();
#pragma unroll
    for (int ty = ty0; ty < 32; ty += 8)
        Vt[(size_t)(bc * 32 + ty) * 2048 + bt * 32 + tx] = (__bf16)tile[tx][ty];
}

// ---------------- Flash attention ----------------
// Block = 16 Q-rows x 4 heads (wave w -> head hg*4+w), KV chunk 384 (<=12 tiles of 32).
// Slot map per head-group: nsplit(g)=ceil((g+1)/24), f(g)=prefix sum; 408 slots, grid (2,408).
// K/V staged once per block (shared by 4 heads): global->VGPR prefetch + ds_write padded rows.
__global__ __launch_bounds__(256) void attn_kernel(const __bf16* __restrict__ Q,
                                                   const __bf16* __restrict__ Kg,
                                                   const __bf16* __restrict__ Vt,
                                                   __bf16* __restrict__ Opart,
                                                   float2* __restrict__ Ml) {
    __shared__ __attribute__((aligned(16))) __bf16 Ks[32 * 264];   // [kv][256+8]
    __shared__ __attribute__((aligned(16))) __bf16 Vs[256 * 40];   // [d][32+8]
    __shared__ __attribute__((aligned(16))) __bf16 Ps[4][16][40];

    int hg = blockIdx.x;
    int rs = 407 - (int)blockIdx.y;  // heavy-first
    int k, base;
    if (rs < 24)       { k = 1; base = 0; }
    else if (rs < 72)  { k = 2; base = 24; }
    else if (rs < 144) { k = 3; base = 72; }
    else if (rs < 240) { k = 4; base = 144; }
    else if (rs < 360) { k = 5; base = 240; }
    else               { k = 6; base = 360; }
    int idx = rs - base;
    int s = idx % k;
    int g = (k - 1) * 24 + idx / k;
    int slot = base + idx - s;  // f(g)

    int start = s * 384;
    int end = g * 16 + 16;
    if (end > start + 384) end = start + 384;
    int ntiles = (end - start + 31) >> 5;

    int tid = threadIdx.x, lane = tid & 63, w = tid >> 6;
    int r = lane & 15, q4 = lane >> 4;
    int h = hg * 4 + w;

    // staging indices
    int krow = w * 8 + (lane & 7);
    int kcol = (lane >> 3) * 32;
    int vrow = w * 64 + lane;
    __bf16* kd = &Ks[krow * 264 + kcol];
    __bf16* vd = &Vs[vrow * 40];

    bf16x8 qf[8];
    {
        const __bf16* qrow = Q + (size_t)(g * 16 + r) * 2048 + h * 256 + q4 * 8;
#pragma unroll
        for (int ks = 0; ks < 8; ks++) qf[ks] = *(const bf16x8*)(qrow + ks * 32);
    }

    floatx4 acc[16];
#pragma unroll
    for (int i = 0; i < 16; i++) acc[i] = (floatx4)0.f;
    float m_i[4] = {-3e38f, -3e38f, -3e38f, -3e38f};
    float l_i[4] = {0.f, 0.f, 0.f, 0.f};

    bf16x8 kr[4], vr[4];
    {
        const __bf16* kp = Kg + (size_t)(start + krow) * 256 + kcol;
        const __bf16* vp = Vt + (size_t)vrow * 2048 + start;
#pragma unroll
        for (int j = 0; j < 4; j++) {
            kr[j] = *(const bf16x8*)(kp + j * 8);
            vr[j] = *(const bf16x8*)(vp + j * 8);
        }
    }

    for (int t = 0; t < ntiles; t++) {
        int kt0 = start + t * 32;
        barrier_lgkm();
#pragma unroll
        for (int j = 0; j < 4; j++) {
            *(bf16x8*)(kd + j * 8) = kr[j];
            *(bf16x8*)(vd + j * 8) = vr[j];
        }
        if (t + 1 < ntiles) {
            const __bf16* kp = Kg + (size_t)(kt0 + 32 + krow) * 256 + kcol;
            const __bf16* vp = Vt + (size_t)vrow * 2048 + kt0 + 32;
#pragma unroll
            for (int j = 0; j < 4; j++) {
                kr[j] = *(const bf16x8*)(kp + j * 8);
                vr[j] = *(const bf16x8*)(vp + j * 8);
            }
        }
        barrier_lgkm();

        // S = Q K^T
        floatx4 sc[2];
        sc[0] = (floatx4)0.f; sc[1] = (floatx4)0.f;
#pragma unroll
        for (int ks = 0; ks < 8; ks++) {
#pragma unroll
            for (int nt = 0; nt < 2; nt++) {
                bf16x8 kf = *(const bf16x8*)&Ks[(nt * 16 + r) * 264 + ks * 32 + q4 * 8];
                sc[nt] = __builtin_amdgcn_mfma_f32_16x16x32_bf16(qf[ks], kf, sc[nt], 0, 0, 0);
            }
        }
        if (kt0 + 31 > g * 16) {  // causal mask (wave-uniform branch)
            int qbase = g * 16 + q4 * 4;
#pragma unroll
            for (int nt = 0; nt < 2; nt++) {
                int kpos = kt0 + nt * 16 + r;
#pragma unroll
                for (int i = 0; i < 4; i++)
                    if (kpos > qbase + i) sc[nt][i] = -3e38f;
            }
        }
        float alpha[4];
#pragma unroll
        for (int i = 0; i < 4; i++) {
            float m = fmaxf(sc[0][i], sc[1][i]);
#pragma unroll
            for (int d = 1; d < 16; d <<= 1) m = fmaxf(m, __shfl_xor(m, d, 16));
            float mn = fmaxf(m_i[i], m);
            alpha[i] = __expf(m_i[i] - mn);
            m_i[i] = mn;
        }
        floatx4 p[2];
#pragma unroll
        for (int i = 0; i < 4; i++) {
            p[0][i] = __expf(sc[0][i] - m_i[i]);
            p[1][i] = __expf(sc[1][i] - m_i[i]);
            float sum = p[0][i] + p[1][i];
#pragma unroll
            for (int d = 1; d < 16; d <<= 1) sum += __shfl_xor(sum, d, 16);
            l_i[i] = l_i[i] * alpha[i] + sum;
        }
#pragma unroll
        for (int n16 = 0; n16 < 16; n16++)
#pragma unroll
            for (int i = 0; i < 4; i++) acc[n16][i] *= alpha[i];

        // P: C-layout -> LDS -> A-layout (per-wave region, padded rows)
#pragma unroll
        for (int nt = 0; nt < 2; nt++)
#pragma unroll
            for (int i = 0; i < 4; i++)
                Ps[w][q4 * 4 + i][nt * 16 + r] = (__bf16)p[nt][i];
        __builtin_amdgcn_wave_barrier();
        bf16x8 pf = *(const bf16x8*)&Ps[w][r][q4 * 8];
        __builtin_amdgcn_wave_barrier();

        // O += P V
#pragma unroll
        for (int n16 = 0; n16 < 16; n16++) {
            bf16x8 vf = *(const bf16x8*)&Vs[(n16 * 16 + r) * 40 + q4 * 8];
            acc[n16] = __builtin_amdgcn_mfma_f32_16x16x32_bf16(pf, vf, acc[n16], 0, 0, 0);
        }
    }

    // unnormalized partials: row base = slot*128 + hg*64 + w*16
    size_t base_row = (size_t)(slot + s) * 128 + hg * 64 + w * 16;
#pragma unroll
    for (int n16 = 0; n16 < 16; n16++)
#pragma unroll
        for (int i = 0; i < 4; i++)
            Opart[(base_row + q4 * 4 + i) * 256 + n16 * 16 + r] = (__bf16)acc[n16][i];
    if (r == 0) {
#pragma unroll
        for (int i = 0; i < 4; i++)
            Ml[base_row + q4 * 4 + i] = make_float2(m_i[i], l_i[i]);
    }
}

// ---------------- combine partials -> attn output (bf16 [2048][2048]) ----------------
__global__ __launch_bounds__(256) void combine_kernel(const __bf16* __restrict__ Opart,
                                                      const float2* __restrict__ Ml,
                                                      __bf16* __restrict__ attnb) {
    int wid = blockIdx.x * 4 + (threadIdx.x >> 6);  // (t,h)
    int lane = threadIdx.x & 63;
    int t = wid >> 3, h = wid & 7;
    int g = t >> 4, row = t & 15;
    int hg = h >> 2, w = h & 3;
    int nsp = g / 24 + 1;                       // ceil((g+1)/24)
    int full = g / 24, rem = g % 24;
    int fg = 12 * full * (full + 1) + rem * (full + 1);

    float ms[6], ls[6];
    size_t rbase[6];
    float M = -3e38f;
    for (int s = 0; s < nsp; s++) {
        rbase[s] = (size_t)(fg + s) * 128 + hg * 64 + w * 16 + row;
        float2 ml = Ml[rbase[s]];
        ms[s] = ml.x; ls[s] = ml.y;
        M = fmaxf(M, ml.x);
    }
    float L = 0.f;
    float o[4] = {0.f, 0.f, 0.f, 0.f};
    for (int s = 0; s < nsp; s++) {
        float wsc = __expf(ms[s] - M);
        L += ls[s] * wsc;
        bf16x4 v = *(const bf16x4*)&Opart[rbase[s] * 256 + lane * 4];
#pragma unroll
        for (int j = 0; j < 4; j++) o[j] += wsc * (float)v[j];
    }
    float inv = 1.f / L;
    bf16x4 ov;
#pragma unroll
    for (int j = 0; j < 4; j++) ov[j] = (__bf16)(o[j] * inv);
    *(bf16x4*)&attnb[(size_t)t * 2048 + h * 256 + lane * 4] = ov;
}

// ---------------- add split-K partials -> fp32 output ----------------
__global__ __launch_bounds__(256) void add_out(const __bf16* __restrict__ p0,
                                               const __bf16* __restrict__ p1,
                                               float* __restrict__ out, int n4) {
    int i = blockIdx.x * 256 + threadIdx.x;
    if (i < n4) {
        bf16x4 a = ((const bf16x4*)p0)[i];
        bf16x4 b = ((const bf16x4*)p1)[i];
        float4 o;
        o.x = (float)a[0] + (float)b[0];
        o.y = (float)a[1] + (float)b[1];
        o.z = (float)a[2] + (float)b[2];
        o.w = (float)a[3] + (float)b[3];
        ((float4*)out)[i] = o;
    }
}

extern "C" void kernel_launch(void* const* d_in, const int* in_sizes, int n_in,
                              void* d_out, int out_size, void* d_ws, size_t ws_size,
                              hipStream_t stream) {
    const int* positions = (const int*)d_in[0];
    const float* hidden  = (const float*)d_in[1];
    const float* Wqkv    = (const float*)d_in[2];
    const float* Wo      = (const float*)d_in[3];
    float* out = (float*)d_out;

    char* ws = (char*)d_ws;
    const size_t MB = 1024 * 1024;
    // [0,8)   Ah (bf16 hidden) -> reused as attnb
    // [8,16)  Woh
    // [16,26) Wqkvh            -> after gemm1: Opart/Ml region; after combine: gemm2 partials
    // [26,36) qkv_a (bf16)  [36,46) qkv_b (bf16)
    // [46,54) Qb   [54,55) Kb   [55,56) Vtb
    __bf16* Ah    = (__bf16*)(ws + 0 * MB);
    __bf16* Woh   = (__bf16*)(ws + 8 * MB);
    __bf16* Wqkvh = (__bf16*)(ws + 16 * MB);
    __bf16* qkvp  = (__bf16*)(ws + 26 * MB);   // two 10 MB slices, grid.z indexed
    __bf16* Qb    = (__bf16*)(ws + 46 * MB);
    __bf16* Kb    = (__bf16*)(ws + 54 * MB);
    __bf16* Vtb   = (__bf16*)(ws + 55 * MB);
    __bf16* Opart = (__bf16*)(ws + 16 * MB);   // 26.8 MB (dead Wqkvh+qkv region)
    float2* Ml    = (float2*)(ws + 43 * MB);   // 0.42 MB
    __bf16* attnb = Ah;
    __bf16* gp    = (__bf16*)(ws + 16 * MB);   // gemm2 partials: two 8 MB slices
    __bf16* qkv_a = qkvp;
    __bf16* qkv_b = qkvp + (size_t)2048 * 2560;

    cast_all<<<13312, 256, 0, stream>>>(hidden, Wqkv, Wo, Ah, Wqkvh, Woh);

    // qkv partials = hidden @ Wqkv^T (split-K x2 in one launch)
    gemm_bt_splitk<<<dim3(20, 16, 2), 256, 0, stream>>>(Ah, Wqkvh, qkvp, 2048, 2560, 2048);

    rope_kernel<<<9216, 256, 0, stream>>>(qkv_a, qkv_b, positions, Qb, Kb);
    vtrans_kernel<<<dim3(64, 8), 256, 0, stream>>>(qkv_a, qkv_b, Vtb);

    attn_kernel<<<dim3(2, 408), 256, 0, stream>>>(Qb, Kb, Vtb, Opart, Ml);
    combine_kernel<<<4096, 256, 0, stream>>>(Opart, Ml, attnb);

    // out partials = attn @ Wo^T (split-K x2), then add
    gemm_bt_splitk<<<dim3(16, 16, 2), 256, 0, stream>>>(attnb, Woh, gp, 2048, 2048, 2048);
    add_out<<<4096, 256, 0, stream>>>(gp, gp + (size_t)2048 * 2048, out, 1048576);
}

// Round 5
// 262.652 us; speedup vs baseline: 1.4396x; 1.0993x over previous
//
#include <hip/hip_runtime.h>
#include <hip/hip_bf16.h>

typedef __bf16 bf16x8 __attribute__((ext_vector_type(8)));
typedef __bf16 bf16x4 __attribute__((ext_vector_type(4)));
typedef float floatx4 __attribute__((ext_vector_type(4)));

__device__ __forceinline__ float fast_exp2(float x) {
    return __builtin_amdgcn_exp2f(x);  // raw v_exp_f32
}

__device__ __forceinline__ void load_lds16(const void* g, void* l) {
    __builtin_amdgcn_global_load_lds((const __attribute__((address_space(1))) void*)g,
                                     (__attribute__((address_space(3))) void*)l,
                                     16, 0, 0);
}

// ---- VALU-speed 16-lane reductions via DPP (quad_perm xor1/xor2, row_ror 8/4) ----
template<int CTRL>
__device__ __forceinline__ float fdpp(float x) {
    union { float f; int i; } u, v;
    u.f = x;
    v.i = __builtin_amdgcn_update_dpp(0, u.i, CTRL, 0xf, 0xf, true);
    return v.f;
}
__device__ __forceinline__ float row16_max(float x) {
    x = fmaxf(x, fdpp<0xB1>(x));   // quad_perm [1,0,3,2]  (xor 1)
    x = fmaxf(x, fdpp<0x4E>(x));   // quad_perm [2,3,0,1]  (xor 2)
    x = fmaxf(x, fdpp<0x128>(x));  // row_ror:8            (xor 8 over 16)
    x = fmaxf(x, fdpp<0x124>(x));  // row_ror:4            (completes all-16)
    return x;
}
__device__ __forceinline__ float row16_sum(float x) {
    x += fdpp<0xB1>(x);
    x += fdpp<0x4E>(x);
    x += fdpp<0x128>(x);
    x += fdpp<0x124>(x);
    return x;
}

// ---------------- fused cast fp32 -> bf16 ----------------
__global__ __launch_bounds__(256) void cast_all(const float* __restrict__ hid,
                                                const float* __restrict__ wqkv,
                                                const float* __restrict__ wo,
                                                __bf16* __restrict__ Ah,
                                                __bf16* __restrict__ Wqkvh,
                                                __bf16* __restrict__ Woh) {
    const int n1 = 1048576, n2 = 1310720;
    int i = blockIdx.x * 256 + threadIdx.x;
    const float* in;
    __bf16* out;
    int j;
    if (i < n1) { in = hid; out = Ah; j = i; }
    else if (i < n1 + n2) { in = wqkv; out = Wqkvh; j = i - n1; }
    else { in = wo; out = Woh; j = i - n1 - n2; }
    float4 v = ((const float4*)in)[j];
    bf16x4 o;
    o[0] = (__bf16)v.x; o[1] = (__bf16)v.y; o[2] = (__bf16)v.z; o[3] = (__bf16)v.w;
    ((bf16x4*)out)[j] = o;
}

// ---------------- GEMM: C[M][N] = A[M][K] * B[N][K]^T (bf16 in, OutT out) ----------------
// 128x128 tile, BK=64, global_load_lds width-16 into fragment-order 1KB chunks.
// grid.x = M-tiles (multiple of 8 -> fixed XCD owns fixed A-stripe for L2 residency).
template<typename OutT>
__global__ __launch_bounds__(256) void gemm_bt(const __bf16* __restrict__ A,
                                               const __bf16* __restrict__ B,
                                               OutT* __restrict__ C,
                                               int M, int N, int K) {
    __shared__ __attribute__((aligned(16))) __bf16 As[128 * 64];
    __shared__ __attribute__((aligned(16))) __bf16 Bs[128 * 64];

    int tid = threadIdx.x, lane = tid & 63, w = tid >> 6;
    int wm = (w >> 1) * 64, wn = (w & 1) * 64;
    int bm0 = blockIdx.x * 128, bn0 = blockIdx.y * 128;
    int r = lane & 15, q4 = lane >> 4;
    int rr = lane >> 2, qq = lane & 3;

    floatx4 acc[4][4];
#pragma unroll
    for (int i = 0; i < 4; i++)
#pragma unroll
        for (int j = 0; j < 4; j++) acc[i][j] = (floatx4)0.f;

    for (int k0 = 0; k0 < K; k0 += 64) {
        __syncthreads();
#pragma unroll
        for (int j = 0; j < 4; j++) {
            int c = w * 4 + j;          // chunk 0..15
            int kk = c >> 3, g = c & 7; // kk: 32-wide k half; g: 16-row group
            load_lds16(A + (size_t)(bm0 + g * 16 + rr) * K + k0 + kk * 32 + qq * 8,
                       &As[c * 512 + lane * 8]);
            load_lds16(B + (size_t)(bn0 + g * 16 + rr) * K + k0 + kk * 32 + qq * 8,
                       &Bs[c * 512 + lane * 8]);
        }
        __syncthreads();

#pragma unroll
        for (int kk = 0; kk < 2; kk++) {
            bf16x8 a[4], b[4];
#pragma unroll
            for (int mt = 0; mt < 4; mt++)
                a[mt] = *(const bf16x8*)&As[(kk * 8 + (wm >> 4) + mt) * 512 + r * 32 + q4 * 8];
#pragma unroll
            for (int nt = 0; nt < 4; nt++)
                b[nt] = *(const bf16x8*)&Bs[(kk * 8 + (wn >> 4) + nt) * 512 + r * 32 + q4 * 8];
#pragma unroll
            for (int mt = 0; mt < 4; mt++)
#pragma unroll
                for (int nt = 0; nt < 4; nt++)
                    acc[mt][nt] = __builtin_amdgcn_mfma_f32_16x16x32_bf16(a[mt], b[nt], acc[mt][nt], 0, 0, 0);
        }
    }

#pragma unroll
    for (int mt = 0; mt < 4; mt++)
#pragma unroll
        for (int nt = 0; nt < 4; nt++) {
            int row = bm0 + wm + mt * 16 + q4 * 4;
            int col = bn0 + wn + nt * 16 + r;
#pragma unroll
            for (int i = 0; i < 4; i++)
                C[(size_t)(row + i) * N + col] = (OutT)acc[mt][nt][i];
        }
}

// ---------------- fused RoPE (q,k) + V transpose. qkv is bf16 [2048][2560] ----------------
// Q pre-scaled by head_dim^-0.5 * log2(e) (attn softmax works in exp2 units).
__global__ __launch_bounds__(256) void rope_vtrans(const __bf16* __restrict__ qkv,
                                                   const int* __restrict__ positions,
                                                   __bf16* __restrict__ Qo,
                                                   __bf16* __restrict__ Ko,
                                                   __bf16* __restrict__ Vt) {
    __shared__ float tile[32][33];
    int b = blockIdx.x;
    if (b < 9216) {
        int idx = b * 256 + threadIdx.x;
        int i = idx & 127;
        int th = idx >> 7;
        int head = th % 9;
        int t = th / 9;
        float invf = expf(-(float)i * 0.07195578415606394f);  // 10000^(-i/128)
        float ang = (float)positions[t] * invf;
        float s = sinf(ang), c = cosf(ang);
        size_t off = (size_t)t * 2560 + (head < 8 ? head * 256 : 2048);
        float x1 = (float)qkv[off + i];
        float x2 = (float)qkv[off + i + 128];
        if (head < 8) {
            const float qs = 0.09016844f;  // 0.0625 * log2(e)
            __bf16* dst = Qo + (size_t)t * 2048 + head * 256;
            dst[i]       = (__bf16)((x1 * c - x2 * s) * qs);
            dst[i + 128] = (__bf16)((x2 * c + x1 * s) * qs);
        } else {
            __bf16* dst = Ko + (size_t)t * 256;
            dst[i]       = (__bf16)(x1 * c - x2 * s);
            dst[i + 128] = (__bf16)(x2 * c + x1 * s);
        }
    } else {
        int bb = b - 9216;
        int bt = bb & 63;   // token tile
        int bc = bb >> 6;   // channel tile
        int tx = threadIdx.x & 31;
        int ty0 = threadIdx.x >> 5;
#pragma unroll
        for (int ty = ty0; ty < 32; ty += 8)
            tile[ty][tx] = (float)qkv[(size_t)(bt * 32 + ty) * 2560 + 2304 + bc * 32 + tx];
        __syncthreads();
#pragma unroll
        for (int ty = ty0; ty < 32; ty += 8)
            Vt[(size_t)(bc * 32 + ty) * 2048 + bt * 32 + tx] = (__bf16)tile[tx][ty];
    }
}

// ---------------- Flash attention ----------------
// Block = 16 Q-rows x 4 heads (wave w -> head hg*4+w). KV chunk 384 (<=12 tiles of 32).
// Softmax in exp2 units (Q pre-scaled by log2e). DPP reductions; Ps XOR-swizzled.
__global__ __launch_bounds__(256) void attn_kernel(const __bf16* __restrict__ Q,
                                                   const __bf16* __restrict__ Kg,
                                                   const __bf16* __restrict__ Vt,
                                                   __bf16* __restrict__ Opart,
                                                   float2* __restrict__ Ml) {
    __shared__ __attribute__((aligned(16))) __bf16 Ks[32 * 264];   // [kv][256+8]
    __shared__ __attribute__((aligned(16))) __bf16 Vs[256 * 40];   // [d][32+8]
    __shared__ __attribute__((aligned(16))) __bf16 Ps[4][16][40];  // XOR-swizzled cols

    int hg = blockIdx.x;
    int rs = 407 - (int)blockIdx.y;  // heavy-first
    int k, base;
    if (rs < 24)       { k = 1; base = 0; }
    else if (rs < 72)  { k = 2; base = 24; }
    else if (rs < 144) { k = 3; base = 72; }
    else if (rs < 240) { k = 4; base = 144; }
    else if (rs < 360) { k = 5; base = 240; }
    else               { k = 6; base = 360; }
    int idx = rs - base;
    int s = idx % k;
    int g = (k - 1) * 24 + idx / k;
    int slot = base + idx - s;  // f(g)

    int start = s * 384;
    int end = g * 16 + 16;
    if (end > start + 384) end = start + 384;
    int ntiles = (end - start + 31) >> 5;

    int tid = threadIdx.x, lane = tid & 63, w = tid >> 6;
    int r = lane & 15, q4 = lane >> 4;
    int h = hg * 4 + w;

    int krow = w * 8 + (lane & 7);
    int kcol = (lane >> 3) * 32;
    int vrow = w * 64 + lane;
    __bf16* kd = &Ks[krow * 264 + kcol];
    __bf16* vd = &Vs[vrow * 40];

    bf16x8 qf[8];
    {
        const __bf16* qrow = Q + (size_t)(g * 16 + r) * 2048 + h * 256 + q4 * 8;
#pragma unroll
        for (int ks = 0; ks < 8; ks++) qf[ks] = *(const bf16x8*)(qrow + ks * 32);
    }

    floatx4 acc[16];
#pragma unroll
    for (int i = 0; i < 16; i++) acc[i] = (floatx4)0.f;
    float m_i[4] = {-3e38f, -3e38f, -3e38f, -3e38f};
    float l_i[4] = {0.f, 0.f, 0.f, 0.f};

    bf16x8 kr[4], vr[4];
    {
        const __bf16* kp = Kg + (size_t)(start + krow) * 256 + kcol;
        const __bf16* vp = Vt + (size_t)vrow * 2048 + start;
#pragma unroll
        for (int j = 0; j < 4; j++) {
            kr[j] = *(const bf16x8*)(kp + j * 8);
            vr[j] = *(const bf16x8*)(vp + j * 8);
        }
    }

    for (int t = 0; t < ntiles; t++) {
        int kt0 = start + t * 32;
        asm volatile("s_waitcnt lgkmcnt(0)\n\ts_barrier" ::: "memory");
#pragma unroll
        for (int j = 0; j < 4; j++) {
            *(bf16x8*)(kd + j * 8) = kr[j];
            *(bf16x8*)(vd + j * 8) = vr[j];
        }
        if (t + 1 < ntiles) {
            const __bf16* kp = Kg + (size_t)(kt0 + 32 + krow) * 256 + kcol;
            const __bf16* vp = Vt + (size_t)vrow * 2048 + kt0 + 32;
#pragma unroll
            for (int j = 0; j < 4; j++) {
                kr[j] = *(const bf16x8*)(kp + j * 8);
                vr[j] = *(const bf16x8*)(vp + j * 8);
            }
        }
        asm volatile("s_waitcnt lgkmcnt(0)\n\ts_barrier" ::: "memory");

        // S = Q K^T (exp2 units)
        floatx4 sc[2];
        sc[0] = (floatx4)0.f; sc[1] = (floatx4)0.f;
#pragma unroll
        for (int ks = 0; ks < 8; ks++) {
#pragma unroll
            for (int nt = 0; nt < 2; nt++) {
                bf16x8 kf = *(const bf16x8*)&Ks[(nt * 16 + r) * 264 + ks * 32 + q4 * 8];
                sc[nt] = __builtin_amdgcn_mfma_f32_16x16x32_bf16(qf[ks], kf, sc[nt], 0, 0, 0);
            }
        }
        if (kt0 + 31 > g * 16) {  // causal mask (wave-uniform branch)
            int qbase = g * 16 + q4 * 4;
#pragma unroll
            for (int nt = 0; nt < 2; nt++) {
                int kpos = kt0 + nt * 16 + r;
#pragma unroll
                for (int i = 0; i < 4; i++)
                    if (kpos > qbase + i) sc[nt][i] = -3e38f;
            }
        }
        float alpha[4];
#pragma unroll
        for (int i = 0; i < 4; i++) {
            float m = row16_max(fmaxf(sc[0][i], sc[1][i]));
            float mn = fmaxf(m_i[i], m);
            alpha[i] = fast_exp2(m_i[i] - mn);
            m_i[i] = mn;
        }
        floatx4 p[2];
#pragma unroll
        for (int i = 0; i < 4; i++) {
            p[0][i] = fast_exp2(sc[0][i] - m_i[i]);
            p[1][i] = fast_exp2(sc[1][i] - m_i[i]);
            float sum = row16_sum(p[0][i] + p[1][i]);
            l_i[i] = l_i[i] * alpha[i] + sum;
        }
#pragma unroll
        for (int n16 = 0; n16 < 16; n16++)
#pragma unroll
            for (int i = 0; i < 4; i++) acc[n16][i] *= alpha[i];

        // P: C-layout -> LDS -> A-layout; col XOR-swizzle kills bank conflicts
#pragma unroll
        for (int nt = 0; nt < 2; nt++)
#pragma unroll
            for (int i = 0; i < 4; i++)
                Ps[w][q4 * 4 + i][(nt * 16 + r) ^ (q4 << 3)] = (__bf16)p[nt][i];
        __builtin_amdgcn_wave_barrier();
        bf16x8 pf = *(const bf16x8*)&Ps[w][r][(q4 * 8) ^ ((r >> 2) << 3)];
        __builtin_amdgcn_wave_barrier();

        // O += P V
#pragma unroll
        for (int n16 = 0; n16 < 16; n16++) {
            bf16x8 vf = *(const bf16x8*)&Vs[(n16 * 16 + r) * 40 + q4 * 8];
            acc[n16] = __builtin_amdgcn_mfma_f32_16x16x32_bf16(pf, vf, acc[n16], 0, 0, 0);
        }
    }

    // unnormalized partials
    size_t base_row = (size_t)(slot + s) * 128 + hg * 64 + w * 16;
#pragma unroll
    for (int n16 = 0; n16 < 16; n16++)
#pragma unroll
        for (int i = 0; i < 4; i++)
            Opart[(base_row + q4 * 4 + i) * 256 + n16 * 16 + r] = (__bf16)acc[n16][i];
    if (r == 0) {
#pragma unroll
        for (int i = 0; i < 4; i++)
            Ml[base_row + q4 * 4 + i] = make_float2(m_i[i], l_i[i]);
    }
}

// ---------------- combine partials -> attn output (bf16 [2048][2048]) ----------------
__global__ __launch_bounds__(256) void combine_kernel(const __bf16* __restrict__ Opart,
                                                      const float2* __restrict__ Ml,
                                                      __bf16* __restrict__ attnb) {
    int wid = blockIdx.x * 4 + (threadIdx.x >> 6);  // (t,h)
    int lane = threadIdx.x & 63;
    int t = wid >> 3, h = wid & 7;
    int g = t >> 4, row = t & 15;
    int hg = h >> 2, w = h & 3;
    int nsp = g / 24 + 1;
    int full = g / 24, rem = g % 24;
    int fg = 12 * full * (full + 1) + rem * (full + 1);

    float ms[6], ls[6];
    size_t rbase[6];
    float M = -3e38f;
    for (int s = 0; s < nsp; s++) {
        rbase[s] = (size_t)(fg + s) * 128 + hg * 64 + w * 16 + row;
        float2 ml = Ml[rbase[s]];
        ms[s] = ml.x; ls[s] = ml.y;
        M = fmaxf(M, ml.x);
    }
    float L = 0.f;
    float o[4] = {0.f, 0.f, 0.f, 0.f};
    for (int s = 0; s < nsp; s++) {
        float wsc = fast_exp2(ms[s] - M);
        L += ls[s] * wsc;
        bf16x4 v = *(const bf16x4*)&Opart[rbase[s] * 256 + lane * 4];
#pragma unroll
        for (int j = 0; j < 4; j++) o[j] += wsc * (float)v[j];
    }
    float inv = 1.f / L;
    bf16x4 ov;
#pragma unroll
    for (int j = 0; j < 4; j++) ov[j] = (__bf16)(o[j] * inv);
    *(bf16x4*)&attnb[(size_t)t * 2048 + h * 256 + lane * 4] = ov;
}

extern "C" void kernel_launch(void* const* d_in, const int* in_sizes, int n_in,
                              void* d_out, int out_size, void* d_ws, size_t ws_size,
                              hipStream_t stream) {
    const int* positions = (const int*)d_in[0];
    const float* hidden  = (const float*)d_in[1];
    const float* Wqkv    = (const float*)d_in[2];
    const float* Wo      = (const float*)d_in[3];
    float* out = (float*)d_out;

    char* ws = (char*)d_ws;
    const size_t MB = 1024 * 1024;
    // [0,8)   Ah (bf16 hidden) -> reused as attnb
    // [8,16)  Woh
    // [16,24) Qb   [24,25) Kb   [25,26) Vtb
    // [26,36) Wqkvh  --+ dead after rope_vtrans: overlaid by Opart (25.5 MB) + Ml
    // [36,46) qkvb   --+
    __bf16* Ah    = (__bf16*)(ws + 0 * MB);
    __bf16* Woh   = (__bf16*)(ws + 8 * MB);
    __bf16* Qb    = (__bf16*)(ws + 16 * MB);
    __bf16* Kb    = (__bf16*)(ws + 24 * MB);
    __bf16* Vtb   = (__bf16*)(ws + 25 * MB);
    __bf16* Wqkvh = (__bf16*)(ws + 26 * MB);
    __bf16* qkvb  = (__bf16*)(ws + 36 * MB);
    __bf16* Opart = (__bf16*)(ws + 26 * MB);   // 408*128*256*2 = 25.5 MB
    float2* Ml    = (float2*)(ws + 52 * MB);   // 0.42 MB
    __bf16* attnb = Ah;

    cast_all<<<13312, 256, 0, stream>>>(hidden, Wqkv, Wo, Ah, Wqkvh, Woh);

    // qkv = hidden @ Wqkv^T (bf16 out); grid.x = M-tiles for XCD L2 A-residency
    gemm_bt<__bf16><<<dim3(16, 20), 256, 0, stream>>>(Ah, Wqkvh, qkvb, 2048, 2560, 2048);

    rope_vtrans<<<9728, 256, 0, stream>>>(qkvb, positions, Qb, Kb, Vtb);

    attn_kernel<<<dim3(2, 408), 256, 0, stream>>>(Qb, Kb, Vtb, Opart, Ml);
    combine_kernel<<<4096, 256, 0, stream>>>(Opart, Ml, attnb);

    // out = attn @ Wo^T (fp32 out)
    gemm_bt<float><<<dim3(16, 16), 256, 0, stream>>>(attnb, Woh, out, 2048, 2048, 2048);
}

// Round 6
// 248.654 us; speedup vs baseline: 1.5207x; 1.0563x over previous
//
#include <hip/hip_runtime.h>
#include <hip/hip_bf16.h>

typedef __bf16 bf16x8 __attribute__((ext_vector_type(8)));
typedef __bf16 bf16x4 __attribute__((ext_vector_type(4)));
typedef float floatx4 __attribute__((ext_vector_type(4)));

__device__ __forceinline__ float fast_exp2(float x) {
    return __builtin_amdgcn_exp2f(x);  // raw v_exp_f32
}

// barrier that drains LDS only — vmem prefetches stay in flight
__device__ __forceinline__ void lds_barrier() {
    asm volatile("s_waitcnt lgkmcnt(0)\n\ts_barrier" ::: "memory");
}

// ---- VALU-speed 16-lane reductions via DPP (quad_perm xor1/xor2, row_ror 8/4) ----
template<int CTRL>
__device__ __forceinline__ float fdpp(float x) {
    union { float f; int i; } u, v;
    u.f = x;
    v.i = __builtin_amdgcn_update_dpp(0, u.i, CTRL, 0xf, 0xf, true);
    return v.f;
}
__device__ __forceinline__ float row16_max(float x) {
    x = fmaxf(x, fdpp<0xB1>(x));   // quad_perm [1,0,3,2]  (xor 1)
    x = fmaxf(x, fdpp<0x4E>(x));   // quad_perm [2,3,0,1]  (xor 2)
    x = fmaxf(x, fdpp<0x128>(x));  // row_ror:8
    x = fmaxf(x, fdpp<0x124>(x));  // row_ror:4
    return x;
}
__device__ __forceinline__ float row16_sum(float x) {
    x += fdpp<0xB1>(x);
    x += fdpp<0x4E>(x);
    x += fdpp<0x128>(x);
    x += fdpp<0x124>(x);
    return x;
}

// ---------------- fused cast fp32 -> bf16 ----------------
__global__ __launch_bounds__(256) void cast_all(const float* __restrict__ hid,
                                                const float* __restrict__ wqkv,
                                                const float* __restrict__ wo,
                                                __bf16* __restrict__ Ah,
                                                __bf16* __restrict__ Wqkvh,
                                                __bf16* __restrict__ Woh) {
    const int n1 = 1048576, n2 = 1310720;
    int i = blockIdx.x * 256 + threadIdx.x;
    const float* in;
    __bf16* out;
    int j;
    if (i < n1) { in = hid; out = Ah; j = i; }
    else if (i < n1 + n2) { in = wqkv; out = Wqkvh; j = i - n1; }
    else { in = wo; out = Woh; j = i - n1 - n2; }
    float4 v = ((const float4*)in)[j];
    bf16x4 o;
    o[0] = (__bf16)v.x; o[1] = (__bf16)v.y; o[2] = (__bf16)v.z; o[3] = (__bf16)v.w;
    ((bf16x4*)out)[j] = o;
}

// ---------------- GEMM: C[M][N] = A[M][K] * B[N][K]^T (bf16 in, OutT out) ----------------
// 128x128 tile, BK=64. Global->VGPR prefetch 1 iter ahead + ds_write staging into
// fragment-order 1KB chunks; lgkm-only barriers keep the prefetch loads in flight
// across the barrier (kills the per-iter vmcnt(0) drain that serializes at 1 block/CU).
template<typename OutT>
__global__ __launch_bounds__(256) void gemm_bt(const __bf16* __restrict__ A,
                                               const __bf16* __restrict__ B,
                                               OutT* __restrict__ C,
                                               int M, int N, int K) {
    __shared__ __attribute__((aligned(16))) __bf16 As[128 * 64];
    __shared__ __attribute__((aligned(16))) __bf16 Bs[128 * 64];

    int tid = threadIdx.x, lane = tid & 63, w = tid >> 6;
    int wm = (w >> 1) * 64, wn = (w & 1) * 64;
    int bm0 = blockIdx.x * 128, bn0 = blockIdx.y * 128;
    int r = lane & 15, q4 = lane >> 4;
    int rr = lane >> 2, qq = lane & 3;

    // staging map: chunk c = w*4+j (1KB); (kk,g) from c; element = A[g*16+rr][kk*32+qq*8]
    const __bf16* Agp[4];
    const __bf16* Bgp[4];
    __bf16* Asd[4];
    __bf16* Bsd[4];
#pragma unroll
    for (int j = 0; j < 4; j++) {
        int c = w * 4 + j;
        int kk = c >> 3, g = c & 7;
        Agp[j] = A + (size_t)(bm0 + g * 16 + rr) * K + kk * 32 + qq * 8;
        Bgp[j] = B + (size_t)(bn0 + g * 16 + rr) * K + kk * 32 + qq * 8;
        Asd[j] = &As[c * 512 + lane * 8];
        Bsd[j] = &Bs[c * 512 + lane * 8];
    }

    floatx4 acc[4][4];
#pragma unroll
    for (int i = 0; i < 4; i++)
#pragma unroll
        for (int j = 0; j < 4; j++) acc[i][j] = (floatx4)0.f;

    bf16x8 ar[4], br[4];
#pragma unroll
    for (int j = 0; j < 4; j++) {
        ar[j] = *(const bf16x8*)Agp[j];
        br[j] = *(const bf16x8*)Bgp[j];
    }

    for (int k0 = 0; k0 < K; k0 += 64) {
        lds_barrier();  // prev iter's frag reads done
#pragma unroll
        for (int j = 0; j < 4; j++) {
            *(bf16x8*)Asd[j] = ar[j];
            *(bf16x8*)Bsd[j] = br[j];
        }
        if (k0 + 64 < K) {
#pragma unroll
            for (int j = 0; j < 4; j++) {
                ar[j] = *(const bf16x8*)(Agp[j] + k0 + 64);
                br[j] = *(const bf16x8*)(Bgp[j] + k0 + 64);
            }
        }
        lds_barrier();  // staged tile visible

#pragma unroll
        for (int kk = 0; kk < 2; kk++) {
            bf16x8 a[4], b[4];
#pragma unroll
            for (int mt = 0; mt < 4; mt++)
                a[mt] = *(const bf16x8*)&As[(kk * 8 + (wm >> 4) + mt) * 512 + r * 32 + q4 * 8];
#pragma unroll
            for (int nt = 0; nt < 4; nt++)
                b[nt] = *(const bf16x8*)&Bs[(kk * 8 + (wn >> 4) + nt) * 512 + r * 32 + q4 * 8];
#pragma unroll
            for (int mt = 0; mt < 4; mt++)
#pragma unroll
                for (int nt = 0; nt < 4; nt++)
                    acc[mt][nt] = __builtin_amdgcn_mfma_f32_16x16x32_bf16(a[mt], b[nt], acc[mt][nt], 0, 0, 0);
        }
    }

#pragma unroll
    for (int mt = 0; mt < 4; mt++)
#pragma unroll
        for (int nt = 0; nt < 4; nt++) {
            int row = bm0 + wm + mt * 16 + q4 * 4;
            int col = bn0 + wn + nt * 16 + r;
#pragma unroll
            for (int i = 0; i < 4; i++)
                C[(size_t)(row + i) * N + col] = (OutT)acc[mt][nt][i];
        }
}

// ---------------- fused RoPE (q,k) + V transpose. qkv is bf16 [2048][2560] ----------------
// Q pre-scaled by head_dim^-0.5 * log2(e) (attn softmax works in exp2 units).
__global__ __launch_bounds__(256) void rope_vtrans(const __bf16* __restrict__ qkv,
                                                   const int* __restrict__ positions,
                                                   __bf16* __restrict__ Qo,
                                                   __bf16* __restrict__ Ko,
                                                   __bf16* __restrict__ Vt) {
    __shared__ float tile[32][33];
    int b = blockIdx.x;
    if (b < 9216) {
        int idx = b * 256 + threadIdx.x;
        int i = idx & 127;
        int th = idx >> 7;
        int head = th % 9;
        int t = th / 9;
        float invf = expf(-(float)i * 0.07195578415606394f);  // 10000^(-i/128)
        float ang = (float)positions[t] * invf;
        float s = sinf(ang), c = cosf(ang);
        size_t off = (size_t)t * 2560 + (head < 8 ? head * 256 : 2048);
        float x1 = (float)qkv[off + i];
        float x2 = (float)qkv[off + i + 128];
        if (head < 8) {
            const float qs = 0.09016844f;  // 0.0625 * log2(e)
            __bf16* dst = Qo + (size_t)t * 2048 + head * 256;
            dst[i]       = (__bf16)((x1 * c - x2 * s) * qs);
            dst[i + 128] = (__bf16)((x2 * c + x1 * s) * qs);
        } else {
            __bf16* dst = Ko + (size_t)t * 256;
            dst[i]       = (__bf16)(x1 * c - x2 * s);
            dst[i + 128] = (__bf16)(x2 * c + x1 * s);
        }
    } else {
        int bb = b - 9216;
        int bt = bb & 63;   // token tile
        int bc = bb >> 6;   // channel tile
        int tx = threadIdx.x & 31;
        int ty0 = threadIdx.x >> 5;
#pragma unroll
        for (int ty = ty0; ty < 32; ty += 8)
            tile[ty][tx] = (float)qkv[(size_t)(bt * 32 + ty) * 2560 + 2304 + bc * 32 + tx];
        __syncthreads();
#pragma unroll
        for (int ty = ty0; ty < 32; ty += 8)
            Vt[(size_t)(bc * 32 + ty) * 2048 + bt * 32 + tx] = (__bf16)tile[tx][ty];
    }
}

// ---------------- Flash attention ----------------
// Block = 16 Q-rows x 4 heads (wave w -> head hg*4+w). KV chunk 384 (<=12 tiles of 32).
// Softmax in exp2 units (Q pre-scaled by log2e). DPP reductions; Ps XOR-swizzled.
__global__ __launch_bounds__(256) void attn_kernel(const __bf16* __restrict__ Q,
                                                   const __bf16* __restrict__ Kg,
                                                   const __bf16* __restrict__ Vt,
                                                   __bf16* __restrict__ Opart,
                                                   float2* __restrict__ Ml) {
    __shared__ __attribute__((aligned(16))) __bf16 Ks[32 * 264];   // [kv][256+8]
    __shared__ __attribute__((aligned(16))) __bf16 Vs[256 * 40];   // [d][32+8]
    __shared__ __attribute__((aligned(16))) __bf16 Ps[4][16][40];  // XOR-swizzled cols

    int hg = blockIdx.x;
    int rs = 407 - (int)blockIdx.y;  // heavy-first
    int k, base;
    if (rs < 24)       { k = 1; base = 0; }
    else if (rs < 72)  { k = 2; base = 24; }
    else if (rs < 144) { k = 3; base = 72; }
    else if (rs < 240) { k = 4; base = 144; }
    else if (rs < 360) { k = 5; base = 240; }
    else               { k = 6; base = 360; }
    int idx = rs - base;
    int s = idx % k;
    int g = (k - 1) * 24 + idx / k;
    int slot = base + idx - s;  // f(g)

    int start = s * 384;
    int end = g * 16 + 16;
    if (end > start + 384) end = start + 384;
    int ntiles = (end - start + 31) >> 5;

    int tid = threadIdx.x, lane = tid & 63, w = tid >> 6;
    int r = lane & 15, q4 = lane >> 4;
    int h = hg * 4 + w;

    int krow = w * 8 + (lane & 7);
    int kcol = (lane >> 3) * 32;
    int vrow = w * 64 + lane;
    __bf16* kd = &Ks[krow * 264 + kcol];
    __bf16* vd = &Vs[vrow * 40];

    bf16x8 qf[8];
    {
        const __bf16* qrow = Q + (size_t)(g * 16 + r) * 2048 + h * 256 + q4 * 8;
#pragma unroll
        for (int ks = 0; ks < 8; ks++) qf[ks] = *(const bf16x8*)(qrow + ks * 32);
    }

    floatx4 acc[16];
#pragma unroll
    for (int i = 0; i < 16; i++) acc[i] = (floatx4)0.f;
    float m_i[4] = {-3e38f, -3e38f, -3e38f, -3e38f};
    float l_i[4] = {0.f, 0.f, 0.f, 0.f};

    bf16x8 kr[4], vr[4];
    {
        const __bf16* kp = Kg + (size_t)(start + krow) * 256 + kcol;
        const __bf16* vp = Vt + (size_t)vrow * 2048 + start;
#pragma unroll
        for (int j = 0; j < 4; j++) {
            kr[j] = *(const bf16x8*)(kp + j * 8);
            vr[j] = *(const bf16x8*)(vp + j * 8);
        }
    }

    for (int t = 0; t < ntiles; t++) {
        int kt0 = start + t * 32;
        lds_barrier();
#pragma unroll
        for (int j = 0; j < 4; j++) {
            *(bf16x8*)(kd + j * 8) = kr[j];
            *(bf16x8*)(vd + j * 8) = vr[j];
        }
        if (t + 1 < ntiles) {
            const __bf16* kp = Kg + (size_t)(kt0 + 32 + krow) * 256 + kcol;
            const __bf16* vp = Vt + (size_t)vrow * 2048 + kt0 + 32;
#pragma unroll
            for (int j = 0; j < 4; j++) {
                kr[j] = *(const bf16x8*)(kp + j * 8);
                vr[j] = *(const bf16x8*)(vp + j * 8);
            }
        }
        lds_barrier();

        // S = Q K^T (exp2 units)
        floatx4 sc[2];
        sc[0] = (floatx4)0.f; sc[1] = (floatx4)0.f;
#pragma unroll
        for (int ks = 0; ks < 8; ks++) {
#pragma unroll
            for (int nt = 0; nt < 2; nt++) {
                bf16x8 kf = *(const bf16x8*)&Ks[(nt * 16 + r) * 264 + ks * 32 + q4 * 8];
                sc[nt] = __builtin_amdgcn_mfma_f32_16x16x32_bf16(qf[ks], kf, sc[nt], 0, 0, 0);
            }
        }
        if (kt0 + 31 > g * 16) {  // causal mask (wave-uniform branch)
            int qbase = g * 16 + q4 * 4;
#pragma unroll
            for (int nt = 0; nt < 2; nt++) {
                int kpos = kt0 + nt * 16 + r;
#pragma unroll
                for (int i = 0; i < 4; i++)
                    if (kpos > qbase + i) sc[nt][i] = -3e38f;
            }
        }
        float alpha[4];
#pragma unroll
        for (int i = 0; i < 4; i++) {
            float m = row16_max(fmaxf(sc[0][i], sc[1][i]));
            float mn = fmaxf(m_i[i], m);
            alpha[i] = fast_exp2(m_i[i] - mn);
            m_i[i] = mn;
        }
        floatx4 p[2];
#pragma unroll
        for (int i = 0; i < 4; i++) {
            p[0][i] = fast_exp2(sc[0][i] - m_i[i]);
            p[1][i] = fast_exp2(sc[1][i] - m_i[i]);
            float sum = row16_sum(p[0][i] + p[1][i]);
            l_i[i] = l_i[i] * alpha[i] + sum;
        }
#pragma unroll
        for (int n16 = 0; n16 < 16; n16++)
#pragma unroll
            for (int i = 0; i < 4; i++) acc[n16][i] *= alpha[i];

        // P: C-layout -> LDS -> A-layout; col XOR-swizzle
#pragma unroll
        for (int nt = 0; nt < 2; nt++)
#pragma unroll
            for (int i = 0; i < 4; i++)
                Ps[w][q4 * 4 + i][(nt * 16 + r) ^ (q4 << 3)] = (__bf16)p[nt][i];
        __builtin_amdgcn_wave_barrier();
        bf16x8 pf = *(const bf16x8*)&Ps[w][r][(q4 * 8) ^ ((r >> 2) << 3)];
        __builtin_amdgcn_wave_barrier();

        // O += P V
#pragma unroll
        for (int n16 = 0; n16 < 16; n16++) {
            bf16x8 vf = *(const bf16x8*)&Vs[(n16 * 16 + r) * 40 + q4 * 8];
            acc[n16] = __builtin_amdgcn_mfma_f32_16x16x32_bf16(pf, vf, acc[n16], 0, 0, 0);
        }
    }

    // unnormalized partials
    size_t base_row = (size_t)(slot + s) * 128 + hg * 64 + w * 16;
#pragma unroll
    for (int n16 = 0; n16 < 16; n16++)
#pragma unroll
        for (int i = 0; i < 4; i++)
            Opart[(base_row + q4 * 4 + i) * 256 + n16 * 16 + r] = (__bf16)acc[n16][i];
    if (r == 0) {
#pragma unroll
        for (int i = 0; i < 4; i++)
            Ml[base_row + q4 * 4 + i] = make_float2(m_i[i], l_i[i]);
    }
}

// ---------------- combine partials -> attn output (bf16 [2048][2048]) ----------------
__global__ __launch_bounds__(256) void combine_kernel(const __bf16* __restrict__ Opart,
                                                      const float2* __restrict__ Ml,
                                                      __bf16* __restrict__ attnb) {
    int wid = blockIdx.x * 4 + (threadIdx.x >> 6);  // (t,h)
    int lane = threadIdx.x & 63;
    int t = wid >> 3, h = wid & 7;
    int g = t >> 4, row = t & 15;
    int hg = h >> 2, w = h & 3;
    int nsp = g / 24 + 1;
    int full = g / 24, rem = g % 24;
    int fg = 12 * full * (full + 1) + rem * (full + 1);

    float ms[6], ls[6];
    size_t rbase[6];
    float M = -3e38f;
    for (int s = 0; s < nsp; s++) {
        rbase[s] = (size_t)(fg + s) * 128 + hg * 64 + w * 16 + row;
        float2 ml = Ml[rbase[s]];
        ms[s] = ml.x; ls[s] = ml.y;
        M = fmaxf(M, ml.x);
    }
    float L = 0.f;
    float o[4] = {0.f, 0.f, 0.f, 0.f};
    for (int s = 0; s < nsp; s++) {
        float wsc = fast_exp2(ms[s] - M);
        L += ls[s] * wsc;
        bf16x4 v = *(const bf16x4*)&Opart[rbase[s] * 256 + lane * 4];
#pragma unroll
        for (int j = 0; j < 4; j++) o[j] += wsc * (float)v[j];
    }
    float inv = 1.f / L;
    bf16x4 ov;
#pragma unroll
    for (int j = 0; j < 4; j++) ov[j] = (__bf16)(o[j] * inv);
    *(bf16x4*)&attnb[(size_t)t * 2048 + h * 256 + lane * 4] = ov;
}

extern "C" void kernel_launch(void* const* d_in, const int* in_sizes, int n_in,
                              void* d_out, int out_size, void* d_ws, size_t ws_size,
                              hipStream_t stream) {
    const int* positions = (const int*)d_in[0];
    const float* hidden  = (const float*)d_in[1];
    const float* Wqkv    = (const float*)d_in[2];
    const float* Wo      = (const float*)d_in[3];
    float* out = (float*)d_out;

    char* ws = (char*)d_ws;
    const size_t MB = 1024 * 1024;
    // [0,8)   Ah (bf16 hidden) -> reused as attnb
    // [8,16)  Woh
    // [16,24) Qb   [24,25) Kb   [25,26) Vtb
    // [26,36) Wqkvh  --+ dead after rope_vtrans: overlaid by Opart (25.5 MB) + Ml
    // [36,46) qkvb   --+
    __bf16* Ah    = (__bf16*)(ws + 0 * MB);
    __bf16* Woh   = (__bf16*)(ws + 8 * MB);
    __bf16* Qb    = (__bf16*)(ws + 16 * MB);
    __bf16* Kb    = (__bf16*)(ws + 24 * MB);
    __bf16* Vtb   = (__bf16*)(ws + 25 * MB);
    __bf16* Wqkvh = (__bf16*)(ws + 26 * MB);
    __bf16* qkvb  = (__bf16*)(ws + 36 * MB);
    __bf16* Opart = (__bf16*)(ws + 26 * MB);   // 408*128*256*2 = 25.5 MB
    float2* Ml    = (float2*)(ws + 52 * MB);   // 0.42 MB
    __bf16* attnb = Ah;

    cast_all<<<13312, 256, 0, stream>>>(hidden, Wqkv, Wo, Ah, Wqkvh, Woh);

    // qkv = hidden @ Wqkv^T (bf16 out)
    gemm_bt<__bf16><<<dim3(16, 20), 256, 0, stream>>>(Ah, Wqkvh, qkvb, 2048, 2560, 2048);

    rope_vtrans<<<9728, 256, 0, stream>>>(qkvb, positions, Qb, Kb, Vtb);

    attn_kernel<<<dim3(2, 408), 256, 0, stream>>>(Qb, Kb, Vtb, Opart, Ml);
    combine_kernel<<<4096, 256, 0, stream>>>(Opart, Ml, attnb);

    // out = attn @ Wo^T (fp32 out)
    gemm_bt<float><<<dim3(16, 16), 256, 0, stream>>>(attnb, Woh, out, 2048, 2048, 2048);
}